// Round 2
// baseline (486.584 us; speedup 1.0000x reference)
//
#include <hip/hip_runtime.h>

// k,v: [B=2, C=128, Hc=48, Wc=48] fp32; NUM_HEADS=8 -> hd=16
// WINDOW=5 -> K=25, r=2; query grid 96x96, scale=2
// Outputs flat: k_nb [2,8,25,16,96,96], v_nb same, mask [2,8,25,96,96]
//
// Key structure: fine rows y=2t and 2t+1 are identical (both anchor to coarse
// row t), and fine cols 4x4..4x4+3 need only coarse cols 2x4, 2x4+1. So one
// thread = one (plane, yc, x4): computes 2 k-vals + 2 v-vals, writes
// 4 float4 stores (2 rows x 2 tensors) = 64 B of k/v output per thread.
// blockIdx.y = plane index -> dy/dx/base are wave-uniform (SALU), the only
// per-lane div is t/24.

#define HC 48
#define WC 48

__global__ __launch_bounds__(384) void fused_expand(
    const float* __restrict__ k, const float* __restrict__ v,
    float* __restrict__ out_k, float* __restrict__ out_v,
    float* __restrict__ out_m) {
    int t  = blockIdx.x * 384 + threadIdx.x;   // 0..1151 within plane
    int yc = t / 24;                           // coarse row 0..47
    int x4 = t - yc * 24;                      // 0..23 (x-quad)
    int by = blockIdx.y;

    if (by < 6400) {
        // kv plane: by = ((b*8+h)*25+kk)*16 + d
        int d    = by & 15;
        int rest = by >> 4;          // (b*8+h)*25 + kk
        int kk   = rest % 25;
        int bh   = rest / 25;        // b*8+h
        int dy = kk / 5 - 2;
        int dx = kk % 5 - 2;

        int yy  = yc + dy;
        bool vy = (unsigned)yy < (unsigned)HC;
        int xc0 = 2 * x4 + dx;
        int xc1 = xc0 + 1;
        bool m0 = vy && ((unsigned)xc0 < (unsigned)WC);
        bool m1 = vy && ((unsigned)xc1 < (unsigned)WC);

        int src = ((bh * 16 + d) * HC + (vy ? yy : 0)) * WC;
        float k0 = m0 ? k[src + xc0] : 0.0f;
        float k1 = m1 ? k[src + xc1] : 0.0f;
        float w0 = m0 ? v[src + xc0] : 0.0f;
        float w1 = m1 ? v[src + xc1] : 0.0f;

        float4 ok = make_float4(k0, k0, k1, k1);
        float4 ov = make_float4(w0, w0, w1, w1);
        // float4 index of (plane, row 2*yc, col 4*x4); next row = +24
        int o = by * 2304 + yc * 48 + x4;
        float4* pk = reinterpret_cast<float4*>(out_k);
        float4* pv = reinterpret_cast<float4*>(out_v);
        pk[o]      = ok;
        pk[o + 24] = ok;
        pv[o]      = ov;
        pv[o + 24] = ov;
    } else {
        // mask plane: q = (b*8+h)*25 + kk
        int q  = by - 6400;
        int kk = q % 25;
        int dy = kk / 5 - 2;
        int dx = kk % 5 - 2;

        int yy  = yc + dy;
        bool vy = (unsigned)yy < (unsigned)HC;
        int xc0 = 2 * x4 + dx;
        bool m0 = vy && ((unsigned)xc0 < (unsigned)WC);
        bool m1 = vy && ((unsigned)(xc0 + 1) < (unsigned)WC);

        float f0 = m0 ? 1.0f : 0.0f;
        float f1 = m1 ? 1.0f : 0.0f;
        float4 m = make_float4(f0, f0, f1, f1);
        int o = q * 2304 + yc * 48 + x4;
        float4* pm = reinterpret_cast<float4*>(out_m);
        pm[o]      = m;
        pm[o + 24] = m;
    }
}

extern "C" void kernel_launch(void* const* d_in, const int* in_sizes, int n_in,
                              void* d_out, int out_size, void* d_ws, size_t ws_size,
                              hipStream_t stream) {
    const float* k = (const float*)d_in[0];
    const float* v = (const float*)d_in[1];
    float* out   = (float*)d_out;
    float* out_k = out;
    float* out_v = out + 58982400;
    float* out_m = out + 117964800;

    // grid: x = 3 blocks x 384 threads = 1152 threads/plane (48 yc x 24 x4)
    //       y = 6400 kv planes + 400 mask planes
    dim3 grid(3, 6800, 1);
    fused_expand<<<grid, 384, 0, stream>>>(k, v, out_k, out_v, out_m);
}

// Round 3
// 482.759 us; speedup vs baseline: 1.0079x; 1.0079x over previous
//
#include <hip/hip_runtime.h>

// k,v: [B=2, C=128, Hc=48, Wc=48] fp32; NUM_HEADS=8 -> hd=16
// WINDOW=5 -> K=25 offsets (r=2); query grid 96x96, scale=2
// Outputs flat fp32: k_nb [2,8,25,16,96,96], v_nb same, mask [2,8,25,96,96]
//
// Structure: a block owns one source channel (b,h,d) x one 24-row coarse
// strip. It stages the strip (+2-row halo, +4-col zero pad) for k and v in
// LDS once, then emits all 25 neighborhood offsets as pure stores:
// per (ycl,x4) thread and per (dy,dx): 4 ds_read_b32 + 4 global_store_dwordx4
// (row-pair duplication: fine rows 2yc,2yc+1 are identical; fine cols
// 4x4..4x4+3 need only coarse cols 2x4,2x4+1). Out-of-range neighbors read
// LDS zeros -> no predication in the kv path. Mask handled by 50 small
// store-only blocks (value independent of b,h -> computed once, stored 16x).

#define ROWS 28          // 24-row strip + 2 halo each side
#define RSTRIDE 56       // padded row stride (floats); data at col offset 4
#define C0 4

__global__ __launch_bounds__(576) void expand_kernel(
    const float* __restrict__ k, const float* __restrict__ v,
    float* __restrict__ out_k, float* __restrict__ out_v,
    float* __restrict__ out_m) {
    int bid = blockIdx.x;
    int tid = threadIdx.x;
    int ycl = tid / 24;          // 0..23 (coarse row within strip)
    int x4  = tid - ycl * 24;    // 0..23 (fine-x quad)

    if (bid < 512) {
        __shared__ float smem[2][ROWS * RSTRIDE];   // [k|v][row][col]

        int ch = bid >> 1;       // 0..255 = b*128 + h*16 + d
        int s  = bid & 1;        // strip 0/1
        int bh = ch >> 4;        // b*8 + h
        int d  = ch & 15;
        int yc0 = 24 * s;

        // --- zero-fill LDS (covers halo rows + col pads) ---
        float4* z = reinterpret_cast<float4*>(&smem[0][0]);
        for (int i = tid; i < 2 * ROWS * RSTRIDE / 4; i += 576)
            z[i] = make_float4(0.f, 0.f, 0.f, 0.f);
        __syncthreads();

        // --- stage valid rows: 28 rows x 12 float4 per tensor ---
        const float4* gk = reinterpret_cast<const float4*>(k) + ch * 576;
        const float4* gv = reinterpret_cast<const float4*>(v) + ch * 576;
        for (int i = tid; i < 2 * ROWS * 12; i += 576) {
            int which = i >= ROWS * 12;
            int j = i - which * ROWS * 12;
            int r = j / 12, c = j - r * 12;
            int g = yc0 - 2 + r;                    // global coarse row
            if ((unsigned)g < 48u) {
                float4 val = which ? gv[g * 12 + c] : gk[g * 12 + c];
                float4* dst = reinterpret_cast<float4*>(
                    &smem[which][r * RSTRIDE + C0 + 4 * c]);
                *dst = val;
            }
        }
        __syncthreads();

        // --- emit 25 offsets ---
        int yc = yc0 + ycl;                          // global coarse row
        const float* sk = &smem[0][(ycl + 2) * RSTRIDE + C0 + 2 * x4];
        const float* sv = &smem[1][(ycl + 2) * RSTRIDE + C0 + 2 * x4];
        // out float4 base for kk=0: plane = (bh*25+kk)*16+d, o = plane*2304 + yc*48 + x4
        long long o = (long long)(bh * 25 * 16 + d) * 2304 + yc * 48 + x4;
        float4* pk = reinterpret_cast<float4*>(out_k);
        float4* pv = reinterpret_cast<float4*>(out_v);

        for (int dy = -2; dy <= 2; ++dy) {
#pragma unroll
            for (int dx = -2; dx <= 2; ++dx) {
                int ld = dy * RSTRIDE + dx;
                float k0 = sk[ld], k1 = sk[ld + 1];
                float w0 = sv[ld], w1 = sv[ld + 1];
                float4 ok = make_float4(k0, k0, k1, k1);
                float4 ov = make_float4(w0, w0, w1, w1);
                pk[o]      = ok;
                pk[o + 24] = ok;
                pv[o]      = ov;
                pv[o + 24] = ov;
                o += 16 * 2304;                     // next kk plane group
            }
        }
    } else {
        // --- mask: 50 blocks, each = one (kk, strip) ---
        int mb = bid - 512;
        int kk = mb >> 1;
        int s  = mb & 1;
        int dy = kk / 5 - 2;
        int dx = kk % 5 - 2;
        int yc = s * 24 + ycl;

        int yy = yc + dy;
        bool vy = (unsigned)yy < 48u;
        int xc0 = 2 * x4 + dx;
        float m0 = (vy && (unsigned)xc0 < 48u) ? 1.0f : 0.0f;
        float m1 = (vy && (unsigned)(xc0 + 1) < 48u) ? 1.0f : 0.0f;
        float4 m = make_float4(m0, m0, m1, m1);

        float4* pm = reinterpret_cast<float4*>(out_m);
        long long o = (long long)kk * 2304 + yc * 48 + x4;
#pragma unroll
        for (int bh = 0; bh < 16; ++bh) {
            pm[o]      = m;
            pm[o + 24] = m;
            o += 57600;                             // next (b,h)
        }
    }
}

extern "C" void kernel_launch(void* const* d_in, const int* in_sizes, int n_in,
                              void* d_out, int out_size, void* d_ws, size_t ws_size,
                              hipStream_t stream) {
    const float* k = (const float*)d_in[0];
    const float* v = (const float*)d_in[1];
    float* out   = (float*)d_out;
    float* out_k = out;
    float* out_v = out + 58982400;
    float* out_m = out + 117964800;

    expand_kernel<<<562, 576, 0, stream>>>(k, v, out_k, out_v, out_m);
}